// Round 9
// baseline (313.028 us; speedup 1.0000x reference)
//
#include <hip/hip_runtime.h>

// weights[M,81] = z[M,256] @ W^T + b (mask at idx 0,1,9); out[M] = sum w*x0^p*x1^k
// fp16 MFMA. B fragments pre-expanded ONCE into d_ws (L2-resident, read from
// global in the kk-loop) -> LDS = 32 KB A-buffer only -> 4 blocks/CU for
// phase-diverse memory streaming. z staged contiguously via LDS (round-5/7
// scheme), LDS-transposed coalesced wout epilogue.

typedef _Float16 half8 __attribute__((ext_vector_type(8)));
typedef __fp16 fp16x2 __attribute__((ext_vector_type(2)));
typedef float f32x4 __attribute__((ext_vector_type(4)));

constexpr int NW = 81;
constexpr int KD = 256;
constexpr int NT = 6;     // col tiles of 16 (real col = 6*cc + n)
constexpr int KT = 8;     // K steps of 32
constexpr int RC = 64;    // rows per chunk (16 per wave)
constexpr int NCH = 4;    // chunks per block -> 256 rows per block

// ---- setup kernel: expand W -> fp16 MFMA B fragments in d_ws (49152 B) ----
__global__ void build_bfrag(const float* __restrict__ W, half8* __restrict__ Bg)
{
    const int i = blockIdx.x * 256 + threadIdx.x;   // [0, NT*KT*64)
    if (i >= NT * KT * 64) return;
    const int n   = i >> 9;
    const int rem = i & 511;
    const int kk  = rem >> 6;
    const int l   = rem & 63;
    const int cc  = l & 15;
    const int col = 6 * cc + n;      // permuted real column
    const int k0i = kk * 32 + ((l >> 4) << 3);
    union { half8 v; fp16x2 p[4]; } u;
    const bool dead = (col > 80) || col == 0 || col == 1 || col == 9;
    if (!dead) {
        const float* wp = W + col * KD + k0i;
        const float4 a = *reinterpret_cast<const float4*>(wp);
        const float4 b = *reinterpret_cast<const float4*>(wp + 4);
        u.p[0] = __builtin_amdgcn_cvt_pkrtz(a.x, a.y);
        u.p[1] = __builtin_amdgcn_cvt_pkrtz(a.z, a.w);
        u.p[2] = __builtin_amdgcn_cvt_pkrtz(b.x, b.y);
        u.p[3] = __builtin_amdgcn_cvt_pkrtz(b.z, b.w);
    } else {
        u.p[0] = __builtin_amdgcn_cvt_pkrtz(0.f, 0.f);
        u.p[1] = u.p[0]; u.p[2] = u.p[0]; u.p[3] = u.p[0];
    }
    Bg[i] = u.v;
}

__global__ __launch_bounds__(256, 4) void poly_mfma(
    const float* __restrict__ x,     // [npos][2]
    const float* __restrict__ z,     // [npos][256]
    const half8* __restrict__ Bg,    // [NT*KT*64] B fragments (L2-resident)
    const float* __restrict__ bias,  // [81]
    float* __restrict__ out,         // [npos]
    float* __restrict__ wout,        // [npos][81]
    int npos)
{
    __shared__ _Float16 Al[RC * KD];            // 32 KiB A chunk (wave-private slices)

    const int tid  = threadIdx.x;
    const int lane = tid & 63;
    const int wv   = tid >> 6;       // wave 0..3
    const int c    = lane & 15;      // MFMA col cc / A row within tile
    const int g    = lane >> 4;      // k-group 0..3

    // per-lane epilogue constants: first idx = 6c -> p0, k0 (k0 in {0,3,6})
    const int p0 = (6 * c) / 9;
    const int k0 = (6 * c) % 9;
    float bv[6];
#pragma unroll
    for (int n = 0; n < 6; ++n) {
        const int idx  = 6 * c + n;
        const int cidx = idx > 80 ? 80 : idx;
        const float bb = bias[cidx];
        const bool dead = (idx > 80) || idx == 0 || idx == 1 || idx == 9;
        bv[n] = dead ? 0.f : bb;
    }

    const int blockbase = blockIdx.x * (RC * NCH);

    // z staging addressing: thread covers 16 float4 (8 rows x 32 B halves).
    // Wave wv touches ONLY rows [wv*16, wv*16+16) of Al.
    const int rl_off = wv * 16 + (lane >> 5);
    const int fo     = (lane & 31) * 8;

    float4 f[16];
    // prologue: contiguous loads of chunk 0
#pragma unroll
    for (int q = 0; q < 8; ++q) {
        int r = blockbase + rl_off + q * 2;
        r = r < npos ? r : npos - 1;
        const float* rp = z + (size_t)r * KD + fo;
        f[q * 2 + 0] = *reinterpret_cast<const float4*>(rp);
        f[q * 2 + 1] = *reinterpret_cast<const float4*>(rp + 4);
    }

    for (int ch = 0; ch < NCH; ++ch) {
        const int rowbase = blockbase + ch * RC;

        if (ch) __syncthreads();   // prior compute/epilogue finished with Al

        // stage chunk ch: cvt fp32->fp16, swizzled ds_write_b128
        {
            const int bytec = (lane & 31) * 16;
#pragma unroll
            for (int q = 0; q < 8; ++q) {
                const int rl = rl_off + q * 2;
                union { half8 v; fp16x2 p[4]; } u;
                u.p[0] = __builtin_amdgcn_cvt_pkrtz(f[q*2].x,   f[q*2].y);
                u.p[1] = __builtin_amdgcn_cvt_pkrtz(f[q*2].z,   f[q*2].w);
                u.p[2] = __builtin_amdgcn_cvt_pkrtz(f[q*2+1].x, f[q*2+1].y);
                u.p[3] = __builtin_amdgcn_cvt_pkrtz(f[q*2+1].z, f[q*2+1].w);
                const int byte = (rl * 512 + bytec) ^ ((rl & 7) << 4);
                *reinterpret_cast<half8*>(reinterpret_cast<char*>(Al) + byte) = u.v;
            }
        }

        __syncthreads();   // Al ready

        // x preload for this wave's 16 epilogue rows
        float2 xp[4];
#pragma unroll
        for (int rg = 0; rg < 4; ++rg) {
            int pp = rowbase + wv * 16 + g * 4 + rg;
            pp = pp < npos ? pp : npos - 1;
            xp[rg] = *reinterpret_cast<const float2*>(x + 2 * (size_t)pp);
        }

        // compute: per kk, 1 A-frag LDS read + 6 B-frag L2 reads + 6 MFMA
        f32x4 acc[NT];
#pragma unroll
        for (int n = 0; n < NT; ++n) acc[n] = (f32x4)(0.f);

#pragma unroll
        for (int kk = 0; kk < KT; ++kk) {
            const int rl = wv * 16 + c;
            const int abyte = (rl * 512 + kk * 64 + g * 16) ^ ((c & 7) << 4);
            const half8 Af = *reinterpret_cast<const half8*>(
                reinterpret_cast<const char*>(Al) + abyte);
#pragma unroll
            for (int n = 0; n < NT; ++n) {
                const half8 Bf = Bg[(n * KT + kk) * 64 + lane];
                acc[n] = __builtin_amdgcn_mfma_f32_16x16x32_f16(Af, Bf, acc[n], 0, 0, 0);
            }
        }

        // issue next chunk's contiguous loads NOW (in flight through epilogue)
        if (ch + 1 < NCH) {
#pragma unroll
            for (int q = 0; q < 8; ++q) {
                int r = rowbase + RC + rl_off + q * 2;
                r = r < npos ? r : npos - 1;
                const float* rp = z + (size_t)r * KD + fo;
                f[q * 2 + 0] = *reinterpret_cast<const float4*>(rp);
                f[q * 2 + 1] = *reinterpret_cast<const float4*>(rp + 4);
            }
        }

        // ---- epilogue: bias, out-reduction, LDS-transposed coalesced wout ----
        char* sbase = reinterpret_cast<char*>(Al) + wv * 8192;

#pragma unroll
        for (int rg = 0; rg < 4; ++rg) {
            const int pos = rowbase + wv * 16 + g * 4 + rg;
            const bool vp = pos < npos;
            const float x0 = xp[rg].x, x1 = xp[rg].y;
            const float x0_2 = x0 * x0, x0_4 = x0_2 * x0_2, x0_8 = x0_4 * x0_4;
            const float x1_2 = x1 * x1, x1_4 = x1_2 * x1_2;
            const float q0sel = ((p0 & 1) ? x0 : 1.f) * ((p0 & 2) ? x0_2 : 1.f)
                              * ((p0 & 4) ? x0_4 : 1.f) * ((p0 & 8) ? x0_8 : 1.f);
            const float q1sel = ((k0 & 1) ? x1 : 1.f) * ((k0 & 2) ? x1_2 : 1.f)
                              * ((k0 & 4) ? x1_4 : 1.f);
            const float qa = q0sel * q1sel;   // x0^p0 * x1^k0 (idx = 6c)
            const float qb = q0sel * x0;      // x0^(p0+1) (wrap target)

            float q = qa;
            float ws[6];
            float wsum = 0.f;
#pragma unroll
            for (int n = 0; n < 6; ++n) {
                const float w = acc[n][rg] + bv[n];  // dead cols: 0 + 0
                ws[n] = w;
                wsum = fmaf(w, q, wsum);
                if (n == 2) q = (k0 == 6) ? qb : q * x1;
                else        q = q * x1;
            }

            // stash into wave-private scratch (scalar b32: rows are 324 B)
            float* srow = reinterpret_cast<float*>(sbase + (g * 4 + rg) * 324);
            if (c < 13) {
#pragma unroll
                for (int n = 0; n < 6; ++n) srow[6 * c + n] = ws[n];
            } else if (c == 13) {
                srow[78] = ws[0]; srow[79] = ws[1]; srow[80] = ws[2];
            }

            wsum += __shfl_xor(wsum, 1, 64);
            wsum += __shfl_xor(wsum, 2, 64);
            wsum += __shfl_xor(wsum, 4, 64);
            wsum += __shfl_xor(wsum, 8, 64);
            if (c == 0 && vp) out[pos] = wsum;
        }

        // wave-coalesced copy: scratch (5184 B) -> wout, aligned float4s
        const int rowstart = rowbase + wv * 16;
        float* gdst = wout + (size_t)rowstart * NW;
        if (rowstart + 16 <= npos) {
#pragma unroll
            for (int j = 0; j < 5; ++j) {
                const int idx = j * 64 + lane;
                const f32x4 v = *reinterpret_cast<const f32x4*>(sbase + idx * 16);
                *reinterpret_cast<f32x4*>(gdst + idx * 4) = v;
            }
            if (lane < 4) {   // tail: idx 320..323
                const int idx = 320 + lane;
                const f32x4 v = *reinterpret_cast<const f32x4*>(sbase + idx * 16);
                *reinterpret_cast<f32x4*>(gdst + idx * 4) = v;
            }
        } else {
            const float* sfl = reinterpret_cast<const float*>(sbase);
            for (int t = lane; t < 16 * NW; t += 64) {
                const int row = t / NW;
                if (rowstart + row < npos) gdst[t] = sfl[t];
            }
        }
    }
}

extern "C" void kernel_launch(void* const* d_in, const int* in_sizes, int n_in,
                              void* d_out, int out_size, void* d_ws, size_t ws_size,
                              hipStream_t stream) {
    const float* x = (const float*)d_in[0];
    const float* z = (const float*)d_in[1];
    const float* W = (const float*)d_in[2];
    const float* b = (const float*)d_in[3];

    const int npos = in_sizes[0] / 2;   // B*L = 262144
    float* out  = (float*)d_out;        // [npos]
    float* wout = out + npos;           // [npos][81]
    half8* Bg   = (half8*)d_ws;         // 49152 B fragment table

    // 1) expand B fragments (NT*KT*64 = 3072 entries)
    hipLaunchKernelGGL(build_bfrag, dim3(12), dim3(256), 0, stream, W, Bg);

    // 2) main fused GEMM+epilogue
    const int rows_per_block = RC * NCH;   // 256
    const int grid = (npos + rows_per_block - 1) / rows_per_block;
    hipLaunchKernelGGL(poly_mfma, dim3(grid), dim3(256), 0, stream,
                       x, z, Bg, b, out, wout, npos);
}

// Round 10
// 272.999 us; speedup vs baseline: 1.1466x; 1.1466x over previous
//
#include <hip/hip_runtime.h>

// weights[M,81] = z[M,256] @ W^T + b (mask at idx 0,1,9); out[M] = sum w*x0^p*x1^k
// fp16 MFMA. B fragments pre-expanded once into d_ws (L2-resident, read from
// global in the kk-loop) -> LDS = 32 KB A-buffer only. launch_bounds(256,3)
// => VGPR cap 170 (no spill) and 3 blocks/CU for phase-diverse streaming.
// XCD-bijective block swizzle for contiguous-per-XCD z streams.

typedef _Float16 half8 __attribute__((ext_vector_type(8)));
typedef __fp16 fp16x2 __attribute__((ext_vector_type(2)));
typedef float f32x4 __attribute__((ext_vector_type(4)));

constexpr int NW = 81;
constexpr int KD = 256;
constexpr int NT = 6;     // col tiles of 16 (real col = 6*cc + n)
constexpr int KT = 8;     // K steps of 32
constexpr int RC = 64;    // rows per chunk (16 per wave)
constexpr int NCH = 4;    // chunks per block -> 256 rows per block

// ---- setup kernel: expand W -> fp16 MFMA B fragments in d_ws (49152 B) ----
__global__ void build_bfrag(const float* __restrict__ W, half8* __restrict__ Bg)
{
    const int i = blockIdx.x * 256 + threadIdx.x;   // [0, NT*KT*64)
    if (i >= NT * KT * 64) return;
    const int n   = i >> 9;
    const int rem = i & 511;
    const int kk  = rem >> 6;
    const int l   = rem & 63;
    const int cc  = l & 15;
    const int col = 6 * cc + n;      // permuted real column
    const int k0i = kk * 32 + ((l >> 4) << 3);
    union { half8 v; fp16x2 p[4]; } u;
    const bool dead = (col > 80) || col == 0 || col == 1 || col == 9;
    if (!dead) {
        const float* wp = W + col * KD + k0i;
        const float4 a = *reinterpret_cast<const float4*>(wp);
        const float4 b = *reinterpret_cast<const float4*>(wp + 4);
        u.p[0] = __builtin_amdgcn_cvt_pkrtz(a.x, a.y);
        u.p[1] = __builtin_amdgcn_cvt_pkrtz(a.z, a.w);
        u.p[2] = __builtin_amdgcn_cvt_pkrtz(b.x, b.y);
        u.p[3] = __builtin_amdgcn_cvt_pkrtz(b.z, b.w);
    } else {
        u.p[0] = __builtin_amdgcn_cvt_pkrtz(0.f, 0.f);
        u.p[1] = u.p[0]; u.p[2] = u.p[0]; u.p[3] = u.p[0];
    }
    Bg[i] = u.v;
}

__global__ __launch_bounds__(256, 3) void poly_mfma(
    const float* __restrict__ x,     // [npos][2]
    const float* __restrict__ z,     // [npos][256]
    const half8* __restrict__ Bg,    // [NT*KT*64] B fragments (L2-resident)
    const float* __restrict__ bias,  // [81]
    float* __restrict__ out,         // [npos]
    float* __restrict__ wout,        // [npos][81]
    int npos)
{
    __shared__ _Float16 Al[RC * KD];            // 32 KiB A chunk (wave-private slices)

    const int tid  = threadIdx.x;
    const int lane = tid & 63;
    const int wv   = tid >> 6;       // wave 0..3
    const int c    = lane & 15;      // MFMA col cc / A row within tile
    const int g    = lane >> 4;      // k-group 0..3

    // per-lane epilogue constants: first idx = 6c -> p0, k0 (k0 in {0,3,6})
    const int p0 = (6 * c) / 9;
    const int k0 = (6 * c) % 9;
    float bv[6];
#pragma unroll
    for (int n = 0; n < 6; ++n) {
        const int idx  = 6 * c + n;
        const int cidx = idx > 80 ? 80 : idx;
        const float bb = bias[cidx];
        const bool dead = (idx > 80) || idx == 0 || idx == 1 || idx == 9;
        bv[n] = dead ? 0.f : bb;
    }

    // XCD-bijective swizzle (nwg % 8 == 0 for the bench shape; guarded)
    const int nwg = gridDim.x;
    const int bid = blockIdx.x;
    const int swz = ((nwg & 7) == 0) ? ((bid & 7) * (nwg >> 3) + (bid >> 3)) : bid;
    const int blockbase = swz * (RC * NCH);

    // z staging addressing: thread covers 16 float4 (8 rows x 32 B halves).
    // Wave wv touches ONLY rows [wv*16, wv*16+16) of Al.
    const int rl_off = wv * 16 + (lane >> 5);
    const int fo     = (lane & 31) * 8;

    float4 f[16];
    // prologue: contiguous loads of chunk 0
#pragma unroll
    for (int q = 0; q < 8; ++q) {
        int r = blockbase + rl_off + q * 2;
        r = r < npos ? r : npos - 1;
        const float* rp = z + (size_t)r * KD + fo;
        f[q * 2 + 0] = *reinterpret_cast<const float4*>(rp);
        f[q * 2 + 1] = *reinterpret_cast<const float4*>(rp + 4);
    }

    for (int ch = 0; ch < NCH; ++ch) {
        const int rowbase = blockbase + ch * RC;

        if (ch) __syncthreads();   // prior compute/epilogue finished with Al

        // stage chunk ch: cvt fp32->fp16, swizzled ds_write_b128
        {
            const int bytec = (lane & 31) * 16;
#pragma unroll
            for (int q = 0; q < 8; ++q) {
                const int rl = rl_off + q * 2;
                union { half8 v; fp16x2 p[4]; } u;
                u.p[0] = __builtin_amdgcn_cvt_pkrtz(f[q*2].x,   f[q*2].y);
                u.p[1] = __builtin_amdgcn_cvt_pkrtz(f[q*2].z,   f[q*2].w);
                u.p[2] = __builtin_amdgcn_cvt_pkrtz(f[q*2+1].x, f[q*2+1].y);
                u.p[3] = __builtin_amdgcn_cvt_pkrtz(f[q*2+1].z, f[q*2+1].w);
                const int byte = (rl * 512 + bytec) ^ ((rl & 7) << 4);
                *reinterpret_cast<half8*>(reinterpret_cast<char*>(Al) + byte) = u.v;
            }
        }

        __syncthreads();   // Al ready

        // x preload for this wave's 16 epilogue rows
        float2 xp[4];
#pragma unroll
        for (int rg = 0; rg < 4; ++rg) {
            int pp = rowbase + wv * 16 + g * 4 + rg;
            pp = pp < npos ? pp : npos - 1;
            xp[rg] = *reinterpret_cast<const float2*>(x + 2 * (size_t)pp);
        }

        // compute: per kk, 1 A-frag LDS read + 6 B-frag L2 reads + 6 MFMA
        f32x4 acc[NT];
#pragma unroll
        for (int n = 0; n < NT; ++n) acc[n] = (f32x4)(0.f);

#pragma unroll
        for (int kk = 0; kk < KT; ++kk) {
            const int rl = wv * 16 + c;
            const int abyte = (rl * 512 + kk * 64 + g * 16) ^ ((c & 7) << 4);
            const half8 Af = *reinterpret_cast<const half8*>(
                reinterpret_cast<const char*>(Al) + abyte);
#pragma unroll
            for (int n = 0; n < NT; ++n) {
                const half8 Bf = Bg[(n * KT + kk) * 64 + lane];
                acc[n] = __builtin_amdgcn_mfma_f32_16x16x32_f16(Af, Bf, acc[n], 0, 0, 0);
            }
        }

        // issue next chunk's contiguous loads NOW (in flight through epilogue)
        if (ch + 1 < NCH) {
#pragma unroll
            for (int q = 0; q < 8; ++q) {
                int r = rowbase + RC + rl_off + q * 2;
                r = r < npos ? r : npos - 1;
                const float* rp = z + (size_t)r * KD + fo;
                f[q * 2 + 0] = *reinterpret_cast<const float4*>(rp);
                f[q * 2 + 1] = *reinterpret_cast<const float4*>(rp + 4);
            }
        }

        // ---- epilogue: bias, out-reduction, LDS-transposed coalesced wout ----
        char* sbase = reinterpret_cast<char*>(Al) + wv * 8192;

#pragma unroll
        for (int rg = 0; rg < 4; ++rg) {
            const int pos = rowbase + wv * 16 + g * 4 + rg;
            const bool vp = pos < npos;
            const float x0 = xp[rg].x, x1 = xp[rg].y;
            const float x0_2 = x0 * x0, x0_4 = x0_2 * x0_2, x0_8 = x0_4 * x0_4;
            const float x1_2 = x1 * x1, x1_4 = x1_2 * x1_2;
            const float q0sel = ((p0 & 1) ? x0 : 1.f) * ((p0 & 2) ? x0_2 : 1.f)
                              * ((p0 & 4) ? x0_4 : 1.f) * ((p0 & 8) ? x0_8 : 1.f);
            const float q1sel = ((k0 & 1) ? x1 : 1.f) * ((k0 & 2) ? x1_2 : 1.f)
                              * ((k0 & 4) ? x1_4 : 1.f);
            const float qa = q0sel * q1sel;   // x0^p0 * x1^k0 (idx = 6c)
            const float qb = q0sel * x0;      // x0^(p0+1) (wrap target)

            float q = qa;
            float ws[6];
            float wsum = 0.f;
#pragma unroll
            for (int n = 0; n < 6; ++n) {
                const float w = acc[n][rg] + bv[n];  // dead cols: 0 + 0
                ws[n] = w;
                wsum = fmaf(w, q, wsum);
                if (n == 2) q = (k0 == 6) ? qb : q * x1;
                else        q = q * x1;
            }

            // stash into wave-private scratch (scalar b32: rows are 324 B)
            float* srow = reinterpret_cast<float*>(sbase + (g * 4 + rg) * 324);
            if (c < 13) {
#pragma unroll
                for (int n = 0; n < 6; ++n) srow[6 * c + n] = ws[n];
            } else if (c == 13) {
                srow[78] = ws[0]; srow[79] = ws[1]; srow[80] = ws[2];
            }

            wsum += __shfl_xor(wsum, 1, 64);
            wsum += __shfl_xor(wsum, 2, 64);
            wsum += __shfl_xor(wsum, 4, 64);
            wsum += __shfl_xor(wsum, 8, 64);
            if (c == 0 && vp) out[pos] = wsum;
        }

        // wave-coalesced copy: scratch (5184 B) -> wout, aligned float4s
        const int rowstart = rowbase + wv * 16;
        float* gdst = wout + (size_t)rowstart * NW;
        if (rowstart + 16 <= npos) {
#pragma unroll
            for (int j = 0; j < 5; ++j) {
                const int idx = j * 64 + lane;
                const f32x4 v = *reinterpret_cast<const f32x4*>(sbase + idx * 16);
                *reinterpret_cast<f32x4*>(gdst + idx * 4) = v;
            }
            if (lane < 4) {   // tail: idx 320..323
                const int idx = 320 + lane;
                const f32x4 v = *reinterpret_cast<const f32x4*>(sbase + idx * 16);
                *reinterpret_cast<f32x4*>(gdst + idx * 4) = v;
            }
        } else {
            const float* sfl = reinterpret_cast<const float*>(sbase);
            for (int t = lane; t < 16 * NW; t += 64) {
                const int row = t / NW;
                if (rowstart + row < npos) gdst[t] = sfl[t];
            }
        }
    }
}

extern "C" void kernel_launch(void* const* d_in, const int* in_sizes, int n_in,
                              void* d_out, int out_size, void* d_ws, size_t ws_size,
                              hipStream_t stream) {
    const float* x = (const float*)d_in[0];
    const float* z = (const float*)d_in[1];
    const float* W = (const float*)d_in[2];
    const float* b = (const float*)d_in[3];

    const int npos = in_sizes[0] / 2;   // B*L = 262144
    float* out  = (float*)d_out;        // [npos]
    float* wout = out + npos;           // [npos][81]
    half8* Bg   = (half8*)d_ws;         // 49152 B fragment table

    // 1) expand B fragments (NT*KT*64 = 3072 entries)
    hipLaunchKernelGGL(build_bfrag, dim3(12), dim3(256), 0, stream, W, Bg);

    // 2) main fused GEMM+epilogue
    const int rows_per_block = RC * NCH;   // 256
    const int grid = (npos + rows_per_block - 1) / rows_per_block;
    hipLaunchKernelGGL(poly_mfma, dim3(grid), dim3(256), 0, stream,
                       x, z, Bg, b, out, wout, npos);
}

// Round 11
// 146.258 us; speedup vs baseline: 2.1402x; 1.8666x over previous
//
#include <hip/hip_runtime.h>

// weights[M,81] = z[M,256] @ W^T + b (mask at idx 0,1,9); out[M] = sum w*x0^p*x1^k
// fp16 MFMA. B fragments pre-expanded once into d_ws; read from L2 inside the
// kk-loop (base pointer laundered per chunk to defeat LICM hoisting -> no
// spill). LDS = 32 KB A-buffer only -> 3 blocks/CU (launch_bounds(256,3)).

typedef _Float16 half8 __attribute__((ext_vector_type(8)));
typedef __fp16 fp16x2 __attribute__((ext_vector_type(2)));
typedef float f32x4 __attribute__((ext_vector_type(4)));

constexpr int NW = 81;
constexpr int KD = 256;
constexpr int NT = 6;     // col tiles of 16 (real col = 6*cc + n)
constexpr int KT = 8;     // K steps of 32
constexpr int RC = 64;    // rows per chunk (16 per wave)
constexpr int NCH = 4;    // chunks per block -> 256 rows per block

// ---- setup kernel: expand W -> fp16 MFMA B fragments in d_ws (49152 B) ----
__global__ void build_bfrag(const float* __restrict__ W, half8* __restrict__ Bg)
{
    const int i = blockIdx.x * 256 + threadIdx.x;   // [0, NT*KT*64)
    if (i >= NT * KT * 64) return;
    const int n   = i >> 9;
    const int rem = i & 511;
    const int kk  = rem >> 6;
    const int l   = rem & 63;
    const int cc  = l & 15;
    const int col = 6 * cc + n;      // permuted real column
    const int k0i = kk * 32 + ((l >> 4) << 3);
    union { half8 v; fp16x2 p[4]; } u;
    const bool dead = (col > 80) || col == 0 || col == 1 || col == 9;
    if (!dead) {
        const float* wp = W + col * KD + k0i;
        const float4 a = *reinterpret_cast<const float4*>(wp);
        const float4 b = *reinterpret_cast<const float4*>(wp + 4);
        u.p[0] = __builtin_amdgcn_cvt_pkrtz(a.x, a.y);
        u.p[1] = __builtin_amdgcn_cvt_pkrtz(a.z, a.w);
        u.p[2] = __builtin_amdgcn_cvt_pkrtz(b.x, b.y);
        u.p[3] = __builtin_amdgcn_cvt_pkrtz(b.z, b.w);
    } else {
        u.p[0] = __builtin_amdgcn_cvt_pkrtz(0.f, 0.f);
        u.p[1] = u.p[0]; u.p[2] = u.p[0]; u.p[3] = u.p[0];
    }
    Bg[i] = u.v;
}

__global__ __launch_bounds__(256, 3) void poly_mfma(
    const float* __restrict__ x,     // [npos][2]
    const float* __restrict__ z,     // [npos][256]
    const half8* __restrict__ Bg,    // [NT*KT*64] B fragments (L2-resident)
    const float* __restrict__ bias,  // [81]
    float* __restrict__ out,         // [npos]
    float* __restrict__ wout,        // [npos][81]
    int npos)
{
    __shared__ _Float16 Al[RC * KD];            // 32 KiB A chunk (wave-private slices)

    const int tid  = threadIdx.x;
    const int lane = tid & 63;
    const int wv   = tid >> 6;       // wave 0..3
    const int c    = lane & 15;      // MFMA col cc / A row within tile
    const int g    = lane >> 4;      // k-group 0..3

    // per-lane epilogue constants: first idx = 6c -> p0, k0 (k0 in {0,3,6})
    const int p0 = (6 * c) / 9;
    const int k0 = (6 * c) % 9;
    float bv[6];
#pragma unroll
    for (int n = 0; n < 6; ++n) {
        const int idx  = 6 * c + n;
        const int cidx = idx > 80 ? 80 : idx;
        const float bb = bias[cidx];
        const bool dead = (idx > 80) || idx == 0 || idx == 1 || idx == 9;
        bv[n] = dead ? 0.f : bb;
    }

    // XCD-bijective swizzle (grid = 1024, divisible by 8)
    const int nwg = gridDim.x;
    const int bid = blockIdx.x;
    const int swz = ((nwg & 7) == 0) ? ((bid & 7) * (nwg >> 3) + (bid >> 3)) : bid;
    const int blockbase = swz * (RC * NCH);

    // z staging addressing: thread covers 16 float4 (8 rows x 32 B halves).
    // Wave wv touches ONLY rows [wv*16, wv*16+16) of Al.
    const int rl_off = wv * 16 + (lane >> 5);
    const int fo     = (lane & 31) * 8;

    float4 f[16];
    // prologue: contiguous loads of chunk 0
#pragma unroll
    for (int q = 0; q < 8; ++q) {
        int r = blockbase + rl_off + q * 2;
        r = r < npos ? r : npos - 1;
        const float* rp = z + (size_t)r * KD + fo;
        f[q * 2 + 0] = *reinterpret_cast<const float4*>(rp);
        f[q * 2 + 1] = *reinterpret_cast<const float4*>(rp + 4);
    }

    for (int ch = 0; ch < NCH; ++ch) {
        const int rowbase = blockbase + ch * RC;

        if (ch) __syncthreads();   // prior compute/epilogue finished with Al

        // stage chunk ch: cvt fp32->fp16, swizzled ds_write_b128
        {
            const int bytec = (lane & 31) * 16;
#pragma unroll
            for (int q = 0; q < 8; ++q) {
                const int rl = rl_off + q * 2;
                union { half8 v; fp16x2 p[4]; } u;
                u.p[0] = __builtin_amdgcn_cvt_pkrtz(f[q*2].x,   f[q*2].y);
                u.p[1] = __builtin_amdgcn_cvt_pkrtz(f[q*2].z,   f[q*2].w);
                u.p[2] = __builtin_amdgcn_cvt_pkrtz(f[q*2+1].x, f[q*2+1].y);
                u.p[3] = __builtin_amdgcn_cvt_pkrtz(f[q*2+1].z, f[q*2+1].w);
                const int byte = (rl * 512 + bytec) ^ ((rl & 7) << 4);
                *reinterpret_cast<half8*>(reinterpret_cast<char*>(Al) + byte) = u.v;
            }
        }

        __syncthreads();   // Al ready

        // x preload for this wave's 16 epilogue rows
        float2 xp[4];
#pragma unroll
        for (int rg = 0; rg < 4; ++rg) {
            int pp = rowbase + wv * 16 + g * 4 + rg;
            pp = pp < npos ? pp : npos - 1;
            xp[rg] = *reinterpret_cast<const float2*>(x + 2 * (size_t)pp);
        }

        // Launder the B pointer once per chunk so LICM cannot hoist the 48
        // fragment loads out of the chunk loop (round-9/10 spill cause).
        size_t bq_bits = (size_t)Bg;
        asm volatile("" : "+s"(bq_bits));
        const half8* Bq = (const half8*)bq_bits;

        // compute: per kk, 1 A-frag LDS read + 6 B-frag L2 reads + 6 MFMA
        f32x4 acc[NT];
#pragma unroll
        for (int n = 0; n < NT; ++n) acc[n] = (f32x4)(0.f);

#pragma unroll 2
        for (int kk = 0; kk < KT; ++kk) {
            const int rl = wv * 16 + c;
            const int abyte = (rl * 512 + kk * 64 + g * 16) ^ ((c & 7) << 4);
            const half8 Af = *reinterpret_cast<const half8*>(
                reinterpret_cast<const char*>(Al) + abyte);
#pragma unroll
            for (int n = 0; n < NT; ++n) {
                const half8 Bf = Bq[(n * KT + kk) * 64 + lane];
                acc[n] = __builtin_amdgcn_mfma_f32_16x16x32_f16(Af, Bf, acc[n], 0, 0, 0);
            }
        }

        // issue next chunk's contiguous loads (in flight through epilogue)
        if (ch + 1 < NCH) {
#pragma unroll
            for (int q = 0; q < 8; ++q) {
                int r = rowbase + RC + rl_off + q * 2;
                r = r < npos ? r : npos - 1;
                const float* rp = z + (size_t)r * KD + fo;
                f[q * 2 + 0] = *reinterpret_cast<const float4*>(rp);
                f[q * 2 + 1] = *reinterpret_cast<const float4*>(rp + 4);
            }
        }

        // ---- epilogue: bias, out-reduction, LDS-transposed coalesced wout ----
        char* sbase = reinterpret_cast<char*>(Al) + wv * 8192;

#pragma unroll
        for (int rg = 0; rg < 4; ++rg) {
            const int pos = rowbase + wv * 16 + g * 4 + rg;
            const bool vp = pos < npos;
            const float x0 = xp[rg].x, x1 = xp[rg].y;
            const float x0_2 = x0 * x0, x0_4 = x0_2 * x0_2, x0_8 = x0_4 * x0_4;
            const float x1_2 = x1 * x1, x1_4 = x1_2 * x1_2;
            const float q0sel = ((p0 & 1) ? x0 : 1.f) * ((p0 & 2) ? x0_2 : 1.f)
                              * ((p0 & 4) ? x0_4 : 1.f) * ((p0 & 8) ? x0_8 : 1.f);
            const float q1sel = ((k0 & 1) ? x1 : 1.f) * ((k0 & 2) ? x1_2 : 1.f)
                              * ((k0 & 4) ? x1_4 : 1.f);
            const float qa = q0sel * q1sel;   // x0^p0 * x1^k0 (idx = 6c)
            const float qb = q0sel * x0;      // x0^(p0+1) (wrap target)

            float q = qa;
            float ws[6];
            float wsum = 0.f;
#pragma unroll
            for (int n = 0; n < 6; ++n) {
                const float w = acc[n][rg] + bv[n];  // dead cols: 0 + 0
                ws[n] = w;
                wsum = fmaf(w, q, wsum);
                if (n == 2) q = (k0 == 6) ? qb : q * x1;
                else        q = q * x1;
            }

            // stash into wave-private scratch (scalar b32: rows are 324 B)
            float* srow = reinterpret_cast<float*>(sbase + (g * 4 + rg) * 324);
            if (c < 13) {
#pragma unroll
                for (int n = 0; n < 6; ++n) srow[6 * c + n] = ws[n];
            } else if (c == 13) {
                srow[78] = ws[0]; srow[79] = ws[1]; srow[80] = ws[2];
            }

            wsum += __shfl_xor(wsum, 1, 64);
            wsum += __shfl_xor(wsum, 2, 64);
            wsum += __shfl_xor(wsum, 4, 64);
            wsum += __shfl_xor(wsum, 8, 64);
            if (c == 0 && vp) out[pos] = wsum;
        }

        // wave-coalesced copy: scratch (5184 B) -> wout, aligned float4s
        const int rowstart = rowbase + wv * 16;
        float* gdst = wout + (size_t)rowstart * NW;
        if (rowstart + 16 <= npos) {
#pragma unroll
            for (int j = 0; j < 5; ++j) {
                const int idx = j * 64 + lane;
                const f32x4 v = *reinterpret_cast<const f32x4*>(sbase + idx * 16);
                *reinterpret_cast<f32x4*>(gdst + idx * 4) = v;
            }
            if (lane < 4) {   // tail: idx 320..323
                const int idx = 320 + lane;
                const f32x4 v = *reinterpret_cast<const f32x4*>(sbase + idx * 16);
                *reinterpret_cast<f32x4*>(gdst + idx * 4) = v;
            }
        } else {
            const float* sfl = reinterpret_cast<const float*>(sbase);
            for (int t = lane; t < 16 * NW; t += 64) {
                const int row = t / NW;
                if (rowstart + row < npos) gdst[t] = sfl[t];
            }
        }
    }
}

extern "C" void kernel_launch(void* const* d_in, const int* in_sizes, int n_in,
                              void* d_out, int out_size, void* d_ws, size_t ws_size,
                              hipStream_t stream) {
    const float* x = (const float*)d_in[0];
    const float* z = (const float*)d_in[1];
    const float* W = (const float*)d_in[2];
    const float* b = (const float*)d_in[3];

    const int npos = in_sizes[0] / 2;   // B*L = 262144
    float* out  = (float*)d_out;        // [npos]
    float* wout = out + npos;           // [npos][81]
    half8* Bg   = (half8*)d_ws;         // 49152 B fragment table

    // 1) expand B fragments (NT*KT*64 = 3072 entries)
    hipLaunchKernelGGL(build_bfrag, dim3(12), dim3(256), 0, stream, W, Bg);

    // 2) main fused GEMM+epilogue
    const int rows_per_block = RC * NCH;   // 256
    const int grid = (npos + rows_per_block - 1) / rows_per_block;
    hipLaunchKernelGGL(poly_mfma, dim3(grid), dim3(256), 0, stream,
                       x, z, Bg, b, out, wout, npos);
}

// Round 12
// 82.232 us; speedup vs baseline: 3.8066x; 1.7786x over previous
//
#include <hip/hip_runtime.h>

// weights[M,81] = z[M,256] @ W^T + b (mask at idx 0,1,9); out[M] = sum w*x0^p*x1^k
// fp16 MFMA, Bl(48K)+Al(32K) LDS, contiguous z staging (round-8 champion) with
// ONE change: raw s_barrier instead of __syncthreads. All Al/scratch dataflow
// is wave-private, so barriers are pure rendezvous; raw form skips the
// s_waitcnt vmcnt(0) drain that was killing the cross-chunk load pipeline.

typedef _Float16 half8 __attribute__((ext_vector_type(8)));
typedef __fp16 fp16x2 __attribute__((ext_vector_type(2)));
typedef float f32x4 __attribute__((ext_vector_type(4)));

constexpr int NW = 81;
constexpr int KD = 256;
constexpr int NT = 6;     // col tiles of 16 (real col = 6*cc + n)
constexpr int KT = 8;     // K steps of 32
constexpr int RC = 64;    // rows per chunk (16 per wave)
constexpr int NCH = 8;    // chunks per block -> 512 rows per block

__global__ __launch_bounds__(256, 2) void poly_mfma(
    const float* __restrict__ x,     // [npos][2]
    const float* __restrict__ z,     // [npos][256]
    const float* __restrict__ W,     // [81][256]
    const float* __restrict__ bias,  // [81]
    float* __restrict__ out,         // [npos]
    float* __restrict__ wout,        // [npos][81]
    int npos)
{
    __shared__ _Float16 Bl[NT * KT * 64 * 8];   // 48 KiB B fragments (block-shared)
    __shared__ _Float16 Al[RC * KD];            // 32 KiB A chunk (wave-private slices)

    const int tid  = threadIdx.x;
    const int lane = tid & 63;
    const int wv   = tid >> 6;       // wave 0..3
    const int c    = lane & 15;      // MFMA col cc / A row within tile
    const int g    = lane >> 4;      // k-group 0..3

    // ---- stage W -> fp16 B fragments (permuted cols; masked cols zeroed) ----
    for (int i = tid; i < NT * KT * 64; i += 256) {
        const int n   = i >> 9;
        const int rem = i & 511;
        const int kk  = rem >> 6;
        const int l   = rem & 63;
        const int cc  = l & 15;
        const int col = 6 * cc + n;
        const int k0i = kk * 32 + ((l >> 4) << 3);
        union { half8 v; fp16x2 p[4]; } u;
        const bool dead = (col > 80) || col == 0 || col == 1 || col == 9;
        if (!dead) {
            const float* wp = W + col * KD + k0i;
            const float4 a = *reinterpret_cast<const float4*>(wp);
            const float4 b = *reinterpret_cast<const float4*>(wp + 4);
            u.p[0] = __builtin_amdgcn_cvt_pkrtz(a.x, a.y);
            u.p[1] = __builtin_amdgcn_cvt_pkrtz(a.z, a.w);
            u.p[2] = __builtin_amdgcn_cvt_pkrtz(b.x, b.y);
            u.p[3] = __builtin_amdgcn_cvt_pkrtz(b.z, b.w);
        } else {
            u.p[0] = __builtin_amdgcn_cvt_pkrtz(0.f, 0.f);
            u.p[1] = u.p[0]; u.p[2] = u.p[0]; u.p[3] = u.p[0];
        }
        *reinterpret_cast<half8*>(&Bl[(size_t)i * 8]) = u.v;
    }

    // per-lane epilogue constants: first idx = 6c -> p0, k0 (k0 in {0,3,6})
    const int p0 = (6 * c) / 9;
    const int k0 = (6 * c) % 9;
    float bv[6];
#pragma unroll
    for (int n = 0; n < 6; ++n) {
        const int idx  = 6 * c + n;
        const int cidx = idx > 80 ? 80 : idx;
        const float bb = bias[cidx];
        const bool dead = (idx > 80) || idx == 0 || idx == 1 || idx == 9;
        bv[n] = dead ? 0.f : bb;
    }

    __syncthreads();   // Bl ready (full barrier once; Bl is cross-wave shared)

    const int blockbase = blockIdx.x * (RC * NCH);

    // z staging addressing: thread covers 16 float4 (8 rows x 32 B halves).
    // Wave wv touches ONLY rows [wv*16, wv*16+16) of Al -> wave-private.
    const int rl_off = wv * 16 + (lane >> 5);
    const int fo     = (lane & 31) * 8;

    float4 f[16];
    // prologue: contiguous loads of chunk 0
#pragma unroll
    for (int q = 0; q < 8; ++q) {
        int r = blockbase + rl_off + q * 2;
        r = r < npos ? r : npos - 1;
        const float* rp = z + (size_t)r * KD + fo;
        f[q * 2 + 0] = *reinterpret_cast<const float4*>(rp);
        f[q * 2 + 1] = *reinterpret_cast<const float4*>(rp + 4);
    }

    for (int ch = 0; ch < NCH; ++ch) {
        const int rowbase = blockbase + ch * RC;

        // rendezvous only (no vmcnt drain): prior compute/epilogue done with Al.
        // All Al data is wave-private; this barrier is pure phase alignment.
        __builtin_amdgcn_s_barrier();

        // stage chunk ch: cvt fp32->fp16, swizzled ds_write_b128
        // (compiler inserts the precise vmcnt wait for f's own loads)
        {
            const int bytec = (lane & 31) * 16;
#pragma unroll
            for (int q = 0; q < 8; ++q) {
                const int rl = rl_off + q * 2;
                union { half8 v; fp16x2 p[4]; } u;
                u.p[0] = __builtin_amdgcn_cvt_pkrtz(f[q*2].x,   f[q*2].y);
                u.p[1] = __builtin_amdgcn_cvt_pkrtz(f[q*2].z,   f[q*2].w);
                u.p[2] = __builtin_amdgcn_cvt_pkrtz(f[q*2+1].x, f[q*2+1].y);
                u.p[3] = __builtin_amdgcn_cvt_pkrtz(f[q*2+1].z, f[q*2+1].w);
                const int byte = (rl * 512 + bytec) ^ ((rl & 7) << 4);
                *reinterpret_cast<half8*>(reinterpret_cast<char*>(Al) + byte) = u.v;
            }
        }

        // issue next chunk's contiguous loads NOW; with raw barriers they stay
        // in flight through barrier2 + compute + epilogue + next barrier1.
        if (ch + 1 < NCH) {
#pragma unroll
            for (int q = 0; q < 8; ++q) {
                int r = rowbase + RC + rl_off + q * 2;
                r = r < npos ? r : npos - 1;
                const float* rp = z + (size_t)r * KD + fo;
                f[q * 2 + 0] = *reinterpret_cast<const float4*>(rp);
                f[q * 2 + 1] = *reinterpret_cast<const float4*>(rp + 4);
            }
        }

        __builtin_amdgcn_s_barrier();   // Al ready (rendezvous only)

        // x preload for this wave's 16 epilogue rows
        float2 xp[4];
#pragma unroll
        for (int rg = 0; rg < 4; ++rg) {
            int pp = rowbase + wv * 16 + g * 4 + rg;
            pp = pp < npos ? pp : npos - 1;
            xp[rg] = *reinterpret_cast<const float2*>(x + 2 * (size_t)pp);
        }

        // compute: per kk, 1 A-frag read + 6 B-frag reads + 6 MFMA
        f32x4 acc[NT];
#pragma unroll
        for (int n = 0; n < NT; ++n) acc[n] = (f32x4)(0.f);

#pragma unroll
        for (int kk = 0; kk < KT; ++kk) {
            const int rl = wv * 16 + c;
            const int abyte = (rl * 512 + kk * 64 + g * 16) ^ ((c & 7) << 4);
            const half8 Af = *reinterpret_cast<const half8*>(
                reinterpret_cast<const char*>(Al) + abyte);
#pragma unroll
            for (int n = 0; n < NT; ++n) {
                const half8 Bf = *reinterpret_cast<const half8*>(
                    &Bl[(size_t)((n * KT + kk) * 64 + lane) * 8]);
                acc[n] = __builtin_amdgcn_mfma_f32_16x16x32_f16(Af, Bf, acc[n], 0, 0, 0);
            }
        }

        // ---- epilogue: bias, out-reduction, LDS-transposed coalesced wout ----
        // Wave's Al slice (8 KiB at wv*8192) is free until ITS OWN next stage.
        char* sbase = reinterpret_cast<char*>(Al) + wv * 8192;

#pragma unroll
        for (int rg = 0; rg < 4; ++rg) {
            const int pos = rowbase + wv * 16 + g * 4 + rg;
            const bool vp = pos < npos;
            const float x0 = xp[rg].x, x1 = xp[rg].y;
            const float x0_2 = x0 * x0, x0_4 = x0_2 * x0_2, x0_8 = x0_4 * x0_4;
            const float x1_2 = x1 * x1, x1_4 = x1_2 * x1_2;
            const float q0sel = ((p0 & 1) ? x0 : 1.f) * ((p0 & 2) ? x0_2 : 1.f)
                              * ((p0 & 4) ? x0_4 : 1.f) * ((p0 & 8) ? x0_8 : 1.f);
            const float q1sel = ((k0 & 1) ? x1 : 1.f) * ((k0 & 2) ? x1_2 : 1.f)
                              * ((k0 & 4) ? x1_4 : 1.f);
            const float qa = q0sel * q1sel;   // x0^p0 * x1^k0 (idx = 6c)
            const float qb = q0sel * x0;      // x0^(p0+1) (wrap target)

            float q = qa;
            float ws[6];
            float wsum = 0.f;
#pragma unroll
            for (int n = 0; n < 6; ++n) {
                const float w = acc[n][rg] + bv[n];  // dead cols: 0 + 0
                ws[n] = w;
                wsum = fmaf(w, q, wsum);
                if (n == 2) q = (k0 == 6) ? qb : q * x1;
                else        q = q * x1;
            }

            // stash into wave-private scratch (scalar b32: rows are 324 B)
            float* srow = reinterpret_cast<float*>(sbase + (g * 4 + rg) * 324);
            if (c < 13) {
#pragma unroll
                for (int n = 0; n < 6; ++n) srow[6 * c + n] = ws[n];
            } else if (c == 13) {
                srow[78] = ws[0]; srow[79] = ws[1]; srow[80] = ws[2];
            }

            wsum += __shfl_xor(wsum, 1, 64);
            wsum += __shfl_xor(wsum, 2, 64);
            wsum += __shfl_xor(wsum, 4, 64);
            wsum += __shfl_xor(wsum, 8, 64);
            if (c == 0 && vp) out[pos] = wsum;
        }

        // wave-coalesced copy: scratch (5184 B) -> wout, aligned float4s
        const int rowstart = rowbase + wv * 16;
        float* gdst = wout + (size_t)rowstart * NW;
        if (rowstart + 16 <= npos) {
#pragma unroll
            for (int j = 0; j < 5; ++j) {
                const int idx = j * 64 + lane;
                const f32x4 v = *reinterpret_cast<const f32x4*>(sbase + idx * 16);
                *reinterpret_cast<f32x4*>(gdst + idx * 4) = v;
            }
            if (lane < 4) {   // tail: idx 320..323
                const int idx = 320 + lane;
                const f32x4 v = *reinterpret_cast<const f32x4*>(sbase + idx * 16);
                *reinterpret_cast<f32x4*>(gdst + idx * 4) = v;
            }
        } else {
            const float* sfl = reinterpret_cast<const float*>(sbase);
            for (int t = lane; t < 16 * NW; t += 64) {
                const int row = t / NW;
                if (rowstart + row < npos) gdst[t] = sfl[t];
            }
        }
    }
}

extern "C" void kernel_launch(void* const* d_in, const int* in_sizes, int n_in,
                              void* d_out, int out_size, void* d_ws, size_t ws_size,
                              hipStream_t stream) {
    const float* x = (const float*)d_in[0];
    const float* z = (const float*)d_in[1];
    const float* W = (const float*)d_in[2];
    const float* b = (const float*)d_in[3];

    const int npos = in_sizes[0] / 2;   // B*L = 262144
    float* out  = (float*)d_out;        // [npos]
    float* wout = out + npos;           // [npos][81]

    const int rows_per_block = RC * NCH;   // 512
    const int grid = (npos + rows_per_block - 1) / rows_per_block;
    hipLaunchKernelGGL(poly_mfma, dim3(grid), dim3(256), 0, stream,
                       x, z, W, b, out, wout, npos);
}

// Round 14
// 79.071 us; speedup vs baseline: 3.9588x; 1.0400x over previous
//
#include <hip/hip_runtime.h>

// weights[M,81] = z[M,256] @ W^T + b (mask at idx 0,1,9); out[M] = sum w*x0^p*x1^k
// fp16 MFMA, Bl(48K)+Al(32K) LDS, contiguous z staging, ping-pong register
// double-buffer (round-8 champion) + NONTEMPORAL z loads and wout/out stores
// (nt = bypass L2 allocation for stream-once data).

typedef _Float16 half8 __attribute__((ext_vector_type(8)));
typedef __fp16 fp16x2 __attribute__((ext_vector_type(2)));
typedef float f32x4 __attribute__((ext_vector_type(4)));

constexpr int NW = 81;
constexpr int KD = 256;
constexpr int NT = 6;     // col tiles of 16 (real col = 6*cc + n)
constexpr int KT = 8;     // K steps of 32
constexpr int RC = 64;    // rows per chunk (16 per wave)
constexpr int NCH = 8;    // chunks per block -> 512 rows per block

__global__ __launch_bounds__(256, 2) void poly_mfma(
    const float* __restrict__ x,     // [npos][2]
    const float* __restrict__ z,     // [npos][256]
    const float* __restrict__ W,     // [81][256]
    const float* __restrict__ bias,  // [81]
    float* __restrict__ out,         // [npos]
    float* __restrict__ wout,        // [npos][81]
    int npos)
{
    __shared__ _Float16 Bl[NT * KT * 64 * 8];   // 48 KiB B fragments (block-shared)
    __shared__ _Float16 Al[RC * KD];            // 32 KiB A chunk (wave-private slices)

    const int tid  = threadIdx.x;
    const int lane = tid & 63;
    const int wv   = tid >> 6;       // wave 0..3
    const int c    = lane & 15;      // MFMA col cc / A row within tile
    const int g    = lane >> 4;      // k-group 0..3

    // ---- stage W -> fp16 B fragments (permuted cols; masked cols zeroed) ----
    for (int i = tid; i < NT * KT * 64; i += 256) {
        const int n   = i >> 9;
        const int rem = i & 511;
        const int kk  = rem >> 6;
        const int l   = rem & 63;
        const int cc  = l & 15;
        const int col = 6 * cc + n;
        const int k0i = kk * 32 + ((l >> 4) << 3);
        union { half8 v; fp16x2 p[4]; } u;
        const bool dead = (col > 80) || col == 0 || col == 1 || col == 9;
        if (!dead) {
            const float* wp = W + col * KD + k0i;
            const float4 a = *reinterpret_cast<const float4*>(wp);
            const float4 b = *reinterpret_cast<const float4*>(wp + 4);
            u.p[0] = __builtin_amdgcn_cvt_pkrtz(a.x, a.y);
            u.p[1] = __builtin_amdgcn_cvt_pkrtz(a.z, a.w);
            u.p[2] = __builtin_amdgcn_cvt_pkrtz(b.x, b.y);
            u.p[3] = __builtin_amdgcn_cvt_pkrtz(b.z, b.w);
        } else {
            u.p[0] = __builtin_amdgcn_cvt_pkrtz(0.f, 0.f);
            u.p[1] = u.p[0]; u.p[2] = u.p[0]; u.p[3] = u.p[0];
        }
        *reinterpret_cast<half8*>(&Bl[(size_t)i * 8]) = u.v;
    }

    // per-lane epilogue constants: first idx = 6c -> p0, k0 (k0 in {0,3,6})
    const int p0 = (6 * c) / 9;
    const int k0 = (6 * c) % 9;
    float bv[6];
#pragma unroll
    for (int n = 0; n < 6; ++n) {
        const int idx  = 6 * c + n;
        const int cidx = idx > 80 ? 80 : idx;
        const float bb = bias[cidx];
        const bool dead = (idx > 80) || idx == 0 || idx == 1 || idx == 9;
        bv[n] = dead ? 0.f : bb;
    }

    const int blockbase = blockIdx.x * (RC * NCH);

    // z staging addressing: thread covers 16 f32x4 (8 rows x 32 B halves).
    // Wave wv touches ONLY rows [wv*16, wv*16+16) of Al.
    const int rl_off = wv * 16 + (lane >> 5);
    const int fo     = (lane & 31) * 8;

    f32x4 f[16], f2[16];
    // prologue: contiguous nontemporal loads of chunk 0 into f
#pragma unroll
    for (int q = 0; q < 8; ++q) {
        int r = blockbase + rl_off + q * 2;
        r = r < npos ? r : npos - 1;
        const f32x4* rp = reinterpret_cast<const f32x4*>(z + (size_t)r * KD + fo);
        f[q * 2 + 0] = __builtin_nontemporal_load(rp);
        f[q * 2 + 1] = __builtin_nontemporal_load(rp + 1);
    }

    auto chunk_body = [&](int ch, f32x4 (&fcur)[16], f32x4 (&fnxt)[16]) {
        const int rowbase = blockbase + ch * RC;

        __syncthreads();   // prior compute/epilogue finished with Al

        // issue NEXT chunk's nontemporal loads FIRST (into the other reg set)
        if (ch + 1 < NCH) {
#pragma unroll
            for (int q = 0; q < 8; ++q) {
                int r = rowbase + RC + rl_off + q * 2;
                r = r < npos ? r : npos - 1;
                const f32x4* rp = reinterpret_cast<const f32x4*>(z + (size_t)r * KD + fo);
                fnxt[q * 2 + 0] = __builtin_nontemporal_load(rp);
                fnxt[q * 2 + 1] = __builtin_nontemporal_load(rp + 1);
            }
        }

        // stage chunk ch (fcur's loads were issued a full chunk ago)
        {
            const int bytec = (lane & 31) * 16;
#pragma unroll
            for (int q = 0; q < 8; ++q) {
                const int rl = rl_off + q * 2;
                union { half8 v; fp16x2 p[4]; } u;
                u.p[0] = __builtin_amdgcn_cvt_pkrtz(fcur[q*2].x,   fcur[q*2].y);
                u.p[1] = __builtin_amdgcn_cvt_pkrtz(fcur[q*2].z,   fcur[q*2].w);
                u.p[2] = __builtin_amdgcn_cvt_pkrtz(fcur[q*2+1].x, fcur[q*2+1].y);
                u.p[3] = __builtin_amdgcn_cvt_pkrtz(fcur[q*2+1].z, fcur[q*2+1].w);
                const int byte = (rl * 512 + bytec) ^ ((rl & 7) << 4);
                *reinterpret_cast<half8*>(reinterpret_cast<char*>(Al) + byte) = u.v;
            }
        }

        __syncthreads();   // Al ready

        // x preload for this wave's 16 epilogue rows
        float2 xp[4];
#pragma unroll
        for (int rg = 0; rg < 4; ++rg) {
            int pp = rowbase + wv * 16 + g * 4 + rg;
            pp = pp < npos ? pp : npos - 1;
            xp[rg] = *reinterpret_cast<const float2*>(x + 2 * (size_t)pp);
        }

        // compute: per kk, 1 A-frag read + 6 B-frag reads + 6 MFMA
        f32x4 acc[NT];
#pragma unroll
        for (int n = 0; n < NT; ++n) acc[n] = (f32x4)(0.f);

#pragma unroll
        for (int kk = 0; kk < KT; ++kk) {
            const int rl = wv * 16 + c;
            const int abyte = (rl * 512 + kk * 64 + g * 16) ^ ((c & 7) << 4);
            const half8 Af = *reinterpret_cast<const half8*>(
                reinterpret_cast<const char*>(Al) + abyte);
#pragma unroll
            for (int n = 0; n < NT; ++n) {
                const half8 Bf = *reinterpret_cast<const half8*>(
                    &Bl[(size_t)((n * KT + kk) * 64 + lane) * 8]);
                acc[n] = __builtin_amdgcn_mfma_f32_16x16x32_f16(Af, Bf, acc[n], 0, 0, 0);
            }
        }

        // ---- epilogue: bias, out-reduction, LDS-transposed coalesced wout ----
        char* sbase = reinterpret_cast<char*>(Al) + wv * 8192;

#pragma unroll
        for (int rg = 0; rg < 4; ++rg) {
            const int pos = rowbase + wv * 16 + g * 4 + rg;
            const bool vp = pos < npos;
            const float x0 = xp[rg].x, x1 = xp[rg].y;
            const float x0_2 = x0 * x0, x0_4 = x0_2 * x0_2, x0_8 = x0_4 * x0_4;
            const float x1_2 = x1 * x1, x1_4 = x1_2 * x1_2;
            const float q0sel = ((p0 & 1) ? x0 : 1.f) * ((p0 & 2) ? x0_2 : 1.f)
                              * ((p0 & 4) ? x0_4 : 1.f) * ((p0 & 8) ? x0_8 : 1.f);
            const float q1sel = ((k0 & 1) ? x1 : 1.f) * ((k0 & 2) ? x1_2 : 1.f)
                              * ((k0 & 4) ? x1_4 : 1.f);
            const float qa = q0sel * q1sel;   // x0^p0 * x1^k0 (idx = 6c)
            const float qb = q0sel * x0;      // x0^(p0+1) (wrap target)

            float q = qa;
            float ws[6];
            float wsum = 0.f;
#pragma unroll
            for (int n = 0; n < 6; ++n) {
                const float w = acc[n][rg] + bv[n];  // dead cols: 0 + 0
                ws[n] = w;
                wsum = fmaf(w, q, wsum);
                if (n == 2) q = (k0 == 6) ? qb : q * x1;
                else        q = q * x1;
            }

            // stash into wave-private scratch (scalar b32: rows are 324 B)
            float* srow = reinterpret_cast<float*>(sbase + (g * 4 + rg) * 324);
            if (c < 13) {
#pragma unroll
                for (int n = 0; n < 6; ++n) srow[6 * c + n] = ws[n];
            } else if (c == 13) {
                srow[78] = ws[0]; srow[79] = ws[1]; srow[80] = ws[2];
            }

            wsum += __shfl_xor(wsum, 1, 64);
            wsum += __shfl_xor(wsum, 2, 64);
            wsum += __shfl_xor(wsum, 4, 64);
            wsum += __shfl_xor(wsum, 8, 64);
            if (c == 0 && vp) __builtin_nontemporal_store(wsum, out + pos);
        }

        // wave-coalesced copy: scratch (5184 B) -> wout, nontemporal float4s
        const int rowstart = rowbase + wv * 16;
        float* gdst = wout + (size_t)rowstart * NW;
        if (rowstart + 16 <= npos) {
#pragma unroll
            for (int j = 0; j < 5; ++j) {
                const int idx = j * 64 + lane;
                const f32x4 v = *reinterpret_cast<const f32x4*>(sbase + idx * 16);
                __builtin_nontemporal_store(v, reinterpret_cast<f32x4*>(gdst + idx * 4));
            }
            if (lane < 4) {   // tail: idx 320..323
                const int idx = 320 + lane;
                const f32x4 v = *reinterpret_cast<const f32x4*>(sbase + idx * 16);
                __builtin_nontemporal_store(v, reinterpret_cast<f32x4*>(gdst + idx * 4));
            }
        } else {
            const float* sfl = reinterpret_cast<const float*>(sbase);
            for (int t = lane; t < 16 * NW; t += 64) {
                const int row = t / NW;
                if (rowstart + row < npos) gdst[t] = sfl[t];
            }
        }
    };

    // unroll-by-2 chunk loop with ping-pong register sets (static reg naming)
#pragma unroll
    for (int ch2 = 0; ch2 < NCH; ch2 += 2) {
        chunk_body(ch2,     f,  f2);
        chunk_body(ch2 + 1, f2, f);
    }
}

extern "C" void kernel_launch(void* const* d_in, const int* in_sizes, int n_in,
                              void* d_out, int out_size, void* d_ws, size_t ws_size,
                              hipStream_t stream) {
    const float* x = (const float*)d_in[0];
    const float* z = (const float*)d_in[1];
    const float* W = (const float*)d_in[2];
    const float* b = (const float*)d_in[3];

    const int npos = in_sizes[0] / 2;   // B*L = 262144
    float* out  = (float*)d_out;        // [npos]
    float* wout = out + npos;           // [npos][81]

    const int rows_per_block = RC * NCH;   // 512
    const int grid = (npos + rows_per_block - 1) / rows_per_block;
    hipLaunchKernelGGL(poly_mfma, dim3(grid), dim3(256), 0, stream,
                       x, z, W, b, out, wout, npos);
}